// Round 3
// baseline (9178.751 us; speedup 1.0000x reference)
//
#include <hip/hip_runtime.h>
#include <hip/hip_fp16.h>

// ============================================================================
// LSTM_78176994722094: 2-layer LSTM (B=128, D_IN=128, T=1024, H=512) + fc head.
//
// Round 3: round-2 numerics PASSED first-call validation (absmax 1.22e-4 vs
// threshold 8.84e-4); failure moved to the post-graph-replay re-check. This
// round removes every replay-only failure candidate:
//   1. Workspace shrunk 34.6MB -> 3.7MB: the full xT (32MB) is replaced by a
//      3-slot windowed buffer (W=32 steps, 1MB/slot) refreshed in-scan: during
//      window w (rounds wW..wW+31) wave 2 of each WG writes window w+1's slot
//      ((w+1)%3) with sc0/sc1 stores; the per-round flag release/acquire chain
//      gives happens-before to all consumers. Window 0 is filled by the
//      prepass. (Protects against d_ws overflow corrupting neighboring device
//      allocations -- the prime suspect for "first call passes, replay fails".)
//   2. No hipMemsetAsync: prepass block 0 zeroes flags and out.
//   3. Flag store is __ATOMIC_RELEASE (agent) -- compiler-emitted device-scope
//      release instead of relying on __syncthreads' vmcnt drain semantics.
//
// Structure (verified rounds 1-2): persistent kernel, 8 clusters x 32 WGs
// (256 blocks, 1/CU, 4 waves). Cluster c owns batch rows [16c,16c+16). Each
// wave holds 16 rows of each recurrent matrix as MFMA A-fragments in VGPRs,
// split-precision (hi fp16 + 2^-11*lo fp16, lo on Whh0/Wih1/Wih0). h0/h1
// exchanged per step via device-scope (sc0+sc1) atomics. Layer 1 skewed one
// step behind layer 0 -> ONE flag barrier per round:
//   round r: compute h0[r] (layer0) and h1[r-1] (layer1) from h0[r-1],h1[r-2].
//
// Workspace (<4MB):
//   [0, 1KB)          flags: u32 per (cluster,wg)
//   [64KB, 576KB)     h exchange: [parity2][cluster8][layer2][b16][ch512] fp16
//   [640KB, 640KB+3MB) xTw: [slot3][cluster8][tau32][b16][d128] fp16
// ============================================================================

typedef _Float16 half8 __attribute__((ext_vector_type(8)));
typedef float f32x4 __attribute__((ext_vector_type(4)));
typedef unsigned long long u64;

#define MFMA16(a, b, c) __builtin_amdgcn_mfma_f32_16x16x32_f16((a), (b), (c), 0, 0, 0)

#define WS_FLAGS_OFF 0
#define WS_EXCH_OFF (64 << 10)
#define WS_XTW_OFF (640 << 10)

__device__ __forceinline__ float sigf(float x) {
  return __builtin_amdgcn_rcpf(1.f + exp2f(-1.44269504f * x));
}
__device__ __forceinline__ float tanhf_(float x) {
  return 1.f - 2.f * __builtin_amdgcn_rcpf(1.f + exp2f(2.88539008f * x));
}
__device__ __forceinline__ unsigned short f2h(float x) {
  _Float16 h = (_Float16)x;  // RNE
  unsigned short b;
  __builtin_memcpy(&b, &h, 2);
  return b;
}

// split 8 fp32 weights -> hi fp16 + lo fp16 (lo = (w - hi) * 2^11)
__device__ __forceinline__ void cvt_split(const f32x4& a, const f32x4& b,
                                          half8& hi, half8& lo) {
#pragma unroll
  for (int i = 0; i < 4; ++i) {
    float w0 = a[i], w1 = b[i];
    _Float16 h0 = (_Float16)w0, h1 = (_Float16)w1;
    hi[i] = h0;
    hi[i + 4] = h1;
    lo[i] = (_Float16)((w0 - (float)h0) * 2048.0f);
    lo[i + 4] = (_Float16)((w1 - (float)h1) * 2048.0f);
  }
}
// scale a fragment by 2^-11 (exact exponent shift; v_pk_mul_f16)
__device__ __forceinline__ half8 hscale(half8 v) {
  half8 r;
#pragma unroll
  for (int i = 0; i < 8; ++i) r[i] = v[i] * (_Float16)4.8828125e-4f;
  return r;
}

// ---------------------------------------------------------------------------
// Prepass: fill xTw window 0 (t=0..31) slot 0, zero flags and out.
// Grid 128 blocks = (cluster c, batch-in-cluster b16); 256 threads.
// ---------------------------------------------------------------------------
__global__ void __launch_bounds__(256) prep_kernel(const float* __restrict__ x,
                                                   _Float16* __restrict__ xTw,
                                                   unsigned* __restrict__ flags,
                                                   float* __restrict__ out) {
  const int bid = blockIdx.x;  // 128 = 8c * 16b
  const int c = bid >> 4, b16 = bid & 15;
  const int tid = threadIdx.x;
  if (bid == 0) {
    flags[tid] = 0;   // 256 flags
    out[tid] = 0.f;   // out_size = B*OUT = 256
  }
  const int d = tid & 127, th = tid >> 7;  // th: tau half (0/1)
  const float* src = x + ((size_t)(c * 16 + b16) * 128 + d) * 1024 + th * 16;
  _Float16* dst = xTw + ((size_t)c * 32 + th * 16) * (16 * 128) + b16 * 128 + d;
#pragma unroll
  for (int i = 0; i < 16; ++i) dst[(size_t)i * (16 * 128)] = (_Float16)src[i];
}

// ---------------------------------------------------------------------------
// Persistent scan kernel. MFMA 16x16x32 f16 layouts (verified rounds 1-2):
//   A[m=lane&15][k=(lane>>4)*8+j], B[k][n=lane&15], D[m=(lane>>4)*4+reg][n].
// ---------------------------------------------------------------------------
__global__ void __launch_bounds__(256, 1) lstm_scan(
    const float* __restrict__ Whh0, const float* __restrict__ bih0,
    const float* __restrict__ bhh0, const float* __restrict__ Wih1,
    const float* __restrict__ Whh1, const float* __restrict__ bih1,
    const float* __restrict__ bhh1, const float* __restrict__ fcW,
    const float* __restrict__ fcb, const float* __restrict__ Wih0,
    const float* __restrict__ x, unsigned* __restrict__ flags,
    unsigned short* __restrict__ exch, _Float16* __restrict__ xTw,
    float* __restrict__ out) {
  __shared__ __align__(16) _Float16 hbuf[2][16][520];

  const int tid = threadIdx.x;
  const int c = blockIdx.x >> 5;   // cluster 0..7
  const int wg = blockIdx.x & 31;  // wg in cluster
  const int wave = tid >> 6;
  const int lane = tid & 63;
  const int q = lane >> 4;
  const int bb = lane & 15;
  const int wcl = wg * 4 + wave;  // wave id in cluster: 0..127
  const int chbase = wcl * 4;     // this wave's 4 hidden channels
  const int m = lane & 15;        // A-fragment row id for this lane
  const int arow = (m & 3) * 512 + chbase + (m >> 2);  // i,f,g,o gate order
  unsigned short* xtw16 = (unsigned short*)xTw;

  // ---- one-time: weight A-fragments (hi for all; lo for Whh0/Wih1/Wih0) ----
  half8 fW0[16], fW0lo[16], fW1i[16], fW1ilo[16], fW1h[16], fX[4], fXlo[4];
  {
    const float* p0 = Whh0 + (size_t)arow * 512 + q * 8;
    const float* p1 = Wih1 + (size_t)arow * 512 + q * 8;
    const float* p2 = Whh1 + (size_t)arow * 512 + q * 8;
#pragma unroll
    for (int kt = 0; kt < 16; ++kt) {
      f32x4 a0 = *(const f32x4*)(p0 + kt * 32), b0 = *(const f32x4*)(p0 + kt * 32 + 4);
      cvt_split(a0, b0, fW0[kt], fW0lo[kt]);
      f32x4 a1 = *(const f32x4*)(p1 + kt * 32), b1 = *(const f32x4*)(p1 + kt * 32 + 4);
      cvt_split(a1, b1, fW1i[kt], fW1ilo[kt]);
      f32x4 a2 = *(const f32x4*)(p2 + kt * 32), b2 = *(const f32x4*)(p2 + kt * 32 + 4);
      half8 dummy;
      cvt_split(a2, b2, fW1h[kt], dummy);  // hi only
    }
    const float* p3 = Wih0 + (size_t)arow * 128 + q * 8;
#pragma unroll
    for (int kt = 0; kt < 4; ++kt) {
      f32x4 a3 = *(const f32x4*)(p3 + kt * 32), b3 = *(const f32x4*)(p3 + kt * 32 + 4);
      cvt_split(a3, b3, fX[kt], fXlo[kt]);
    }
  }

  float b0v[4], b1v[4];
#pragma unroll
  for (int g = 0; g < 4; ++g) {
    int rrow = g * 512 + chbase + q;
    b0v[g] = bih0[rrow] + bhh0[rrow];
    b1v[g] = bih1[rrow] + bhh1[rrow];
  }
  const int ch = chbase + q;
  const float fcw0 = fcW[ch], fcw1 = fcW[512 + ch];

  float c0 = 0.f, c1 = 0.f;
  unsigned* myflag = flags + (c * 32 + wg);
  const unsigned* spinflag = flags + (c * 32 + (lane & 31));

  const int T = 1024;
  for (int r = 0; r <= T; ++r) {
    const bool L0 = (r < T);
    const bool L1 = (r > 0);
    const bool L1h = (r > 1);

    // ---- x-window refresh: during window w=r>>5, wave 2 writes window w+1
    //      into slot (w+1)%3. Old content of that slot (window w-2) was fully
    //      consumed before round wW (flag-enforced); new content is consumed
    //      from round (w+1)*32 on, after all WGs posted flag (w+1)*32. ----
    if (wave == 2 && r < 992) {
      const int wnext = (r >> 5) + 1, sw = wnext % 3, rw = r & 31;
      const int bd = wg * 64 + rw * 2 + (lane >> 5);  // (b<<7)|d, 0..2047
      const int xb = bd >> 7, xd = bd & 127, tau = lane & 31;
      float xv = x[((size_t)(c * 16 + xb) * 128 + xd) * 1024 + wnext * 32 + tau];
      __hip_atomic_store(
          xtw16 + (((size_t)(sw * 8 + c) * 32 + tau) * 16 + xb) * 128 + xd,
          f2h(xv), __ATOMIC_RELAXED, __HIP_MEMORY_SCOPE_AGENT);
    }

    // x fragments for t=r from window slot (issued before the spin)
    half8 xf[4];
    if (L0) {
      const int s = (r >> 5) % 3, tau = r & 31;
      const _Float16* xp =
          xTw + (((size_t)(s * 8 + c) * 32 + tau) * 16 + bb) * 128 + q * 8;
#pragma unroll
      for (int kt = 0; kt < 4; ++kt) xf[kt] = *(const half8*)(xp + kt * 32);
    }

    if (r > 0) {
      if (wave == 0) {
        int guard = 0;
        for (;;) {
          unsigned v = __hip_atomic_load(spinflag, __ATOMIC_RELAXED,
                                         __HIP_MEMORY_SCOPE_AGENT);
          if (__ballot(v >= (unsigned)r) == ~0ull) break;
          if (++guard > (1 << 24)) break;  // deadlock bailout
        }
        __builtin_amdgcn_fence(__ATOMIC_ACQUIRE, "agent");
      }
      __syncthreads();
      // stage h0[r-1], h1[r-2] (32KB) into padded LDS rows
      const int p = (r - 1) & 1;
      const u64* src = (const u64*)exch + ((size_t)p * 8 + c) * (32 * 128) + tid;
#pragma unroll
      for (int hh = 0; hh < 2; ++hh) {
        u64 v[8];
#pragma unroll
        for (int i = 0; i < 8; ++i)
          v[i] = __hip_atomic_load(src + (hh * 8 + i) * 256, __ATOMIC_RELAXED,
                                   __HIP_MEMORY_SCOPE_AGENT);
#pragma unroll
        for (int i = 0; i < 8; ++i) {
          int f = (hh * 8 + i) * 256 + tid;
          int row = f >> 7, off = f & 127;  // row = layer*16 + b
          *((u64*)(&hbuf[row >> 4][row & 15][0]) + off) = v[i];
        }
      }
    }
    __syncthreads();

    // ---- MFMA chains (split accumulators; lo-chains share accs via 2^-11-
    //      scaled B operands) ----
    f32x4 accX = {b0v[0], b0v[1], b0v[2], b0v[3]};
    f32x4 a0 = {0.f, 0.f, 0.f, 0.f}, a0b = {0.f, 0.f, 0.f, 0.f};
    if (L0) {
#pragma unroll
      for (int kt = 0; kt < 4; ++kt) {
        accX = MFMA16(fX[kt], xf[kt], accX);
        accX = MFMA16(fXlo[kt], hscale(xf[kt]), accX);
      }
    }
    f32x4 a1 = {b1v[0], b1v[1], b1v[2], b1v[3]};
    f32x4 a1b = {0.f, 0.f, 0.f, 0.f}, a1c = {0.f, 0.f, 0.f, 0.f},
          a1d = {0.f, 0.f, 0.f, 0.f};
    if (L1) {
#pragma unroll
      for (int kt = 0; kt < 8; ++kt) {
        half8 hA = *(const half8*)(&hbuf[0][bb][kt * 32 + q * 8]);
        half8 hB = *(const half8*)(&hbuf[0][bb][(kt + 8) * 32 + q * 8]);
        half8 hAs = hscale(hA), hBs = hscale(hB);
        if (L0) {
          a0 = MFMA16(fW0[kt], hA, a0);
          a0b = MFMA16(fW0[kt + 8], hB, a0b);
          a0 = MFMA16(fW0lo[kt], hAs, a0);
          a0b = MFMA16(fW0lo[kt + 8], hBs, a0b);
        }
        a1 = MFMA16(fW1i[kt], hA, a1);
        a1b = MFMA16(fW1i[kt + 8], hB, a1b);
        a1 = MFMA16(fW1ilo[kt], hAs, a1);
        a1b = MFMA16(fW1ilo[kt + 8], hBs, a1b);
      }
    }
    if (L1h) {
#pragma unroll
      for (int kt = 0; kt < 8; ++kt) {
        half8 hC = *(const half8*)(&hbuf[1][bb][kt * 32 + q * 8]);
        half8 hD = *(const half8*)(&hbuf[1][bb][(kt + 8) * 32 + q * 8]);
        a1c = MFMA16(fW1h[kt], hC, a1c);
        a1d = MFMA16(fW1h[kt + 8], hD, a1d);
      }
    }

    // ---- epilogues: lane (q,b) owns (channel chbase+q, batch c*16+bb) ----
    if (L0) {
      f32x4 g0 = accX + a0 + a0b;
      float gi = sigf(g0.x), gf = sigf(g0.y), gg = tanhf_(g0.z), go = sigf(g0.w);
      c0 = gf * c0 + gi * gg;
      float h0v = go * tanhf_(c0);
      size_t idx = (((size_t)(r & 1) * 8 + c) * 32 + 0 * 16 + bb) * 512 + ch;
      __hip_atomic_store(exch + idx, f2h(h0v), __ATOMIC_RELAXED,
                         __HIP_MEMORY_SCOPE_AGENT);
    }
    if (L1) {
      f32x4 g1 = a1 + a1b + a1c + a1d;
      float gi = sigf(g1.x), gf = sigf(g1.y), gg = tanhf_(g1.z), go = sigf(g1.w);
      c1 = gf * c1 + gi * gg;
      float h1v = go * tanhf_(c1);
      if (r == T) {
        // fc head: reduce the wave's 4 channels, one atomicAdd per (b,o)
        // contributor group (out zeroed by prep_kernel each call).
        float s0 = h1v * fcw0, s1 = h1v * fcw1;
        s0 += __shfl_xor(s0, 16); s0 += __shfl_xor(s0, 32);
        s1 += __shfl_xor(s1, 16); s1 += __shfl_xor(s1, 32);
        if (q == 0) {
          atomicAdd(out + (size_t)(c * 16 + bb) * 2 + 0, s0);
          atomicAdd(out + (size_t)(c * 16 + bb) * 2 + 1, s1);
        }
        if (wcl == 0 && lane < 32)
          atomicAdd(out + (size_t)(c * 16 + (lane & 15)) * 2 + (lane >> 4),
                    fcb[lane >> 4]);
      } else {
        size_t idx = (((size_t)(r & 1) * 8 + c) * 32 + 1 * 16 + bb) * 512 + ch;
        __hip_atomic_store(exch + idx, f2h(h1v), __ATOMIC_RELAXED,
                           __HIP_MEMORY_SCOPE_AGENT);
      }
    }
    if (r == T) break;
    __syncthreads();  // all waves' h stores + refresh stores issued
    if (tid == 0)  // device-scope RELEASE: orders all prior stores before flag
      __hip_atomic_store(myflag, (unsigned)(r + 1), __ATOMIC_RELEASE,
                         __HIP_MEMORY_SCOPE_AGENT);
  }
}

extern "C" void kernel_launch(void* const* d_in, const int* in_sizes, int n_in,
                              void* d_out, int out_size, void* d_ws,
                              size_t ws_size, hipStream_t stream) {
  const float* x = (const float*)d_in[0];
  const float* Wih0 = (const float*)d_in[1];
  const float* Whh0 = (const float*)d_in[2];
  const float* bih0 = (const float*)d_in[3];
  const float* bhh0 = (const float*)d_in[4];
  const float* Wih1 = (const float*)d_in[5];
  const float* Whh1 = (const float*)d_in[6];
  const float* bih1 = (const float*)d_in[7];
  const float* bhh1 = (const float*)d_in[8];
  const float* fcW = (const float*)d_in[9];
  const float* fcb = (const float*)d_in[10];

  char* ws = (char*)d_ws;  // uses < 4MB total
  unsigned* flags = (unsigned*)(ws + WS_FLAGS_OFF);
  unsigned short* exch = (unsigned short*)(ws + WS_EXCH_OFF);
  _Float16* xTw = (_Float16*)(ws + WS_XTW_OFF);
  float* out = (float*)d_out;

  prep_kernel<<<dim3(128), dim3(256), 0, stream>>>(x, xTw, flags, out);
  lstm_scan<<<dim3(256), dim3(256), 0, stream>>>(Whh0, bih0, bhh0, Wih1, Whh1,
                                                 bih1, bhh1, fcW, fcb, Wih0, x,
                                                 flags, exch, xTw, out);
}

// Round 4
// 6665.958 us; speedup vs baseline: 1.3770x; 1.3770x over previous
//
#include <hip/hip_runtime.h>
#include <hip/hip_fp16.h>

// ============================================================================
// LSTM_78176994722094: 2-layer LSTM (B=128, D_IN=128, T=1024, H=512) + fc head.
//
// Round 4 (R3 passed @ 9179us; MfmaUtil 6.4%, VALUBusy 10.3%, HBM 3.4% -> the
// per-round sync path is stall-bound). Three changes:
//  1. NO agent fences (they lower to buffer_wbl2 / buffer_inv = L2 writeback/
//     invalidate per WG per round). All cross-WG data uses relaxed sc0+sc1
//     atomics (MALL-coherent); ordering = __syncthreads vmcnt drain + explicit
//     `s_waitcnt vmcnt(0)` before the flag store. x-window consumer loads are
//     now atomic u64 too (they were plain cached loads relying on the acquire
//     invalidate).
//  2. Coalesced h publication: epilogue writes h to LDS (hout); after the
//     bottom barrier wave 0 issues 2 u64 stores/lane in 32B contiguous
//     segments (16 line-touches/WG instead of 128 scattered 8B touches).
//  3. Coalesced x-refresh: each round the cluster writes ONE tau plane
//     (lane = d -> contiguous 128B rows). The scatter moves to the x *read*
//     side (MALL-resident, no HBM write amplification). Measured WRITE_SIZE
//     1.28 MB/round was ~1 MB refresh amplification + scattered h stores;
//     predict WRITE_SIZE 1.31 GB -> ~0.4 GB.
//
// Structure (verified R1-R3): persistent kernel, 8 clusters x 32 WGs (256
// blocks, 1/CU, 4 waves). Cluster c owns batch rows [16c,16c+16). Each wave
// holds 16 rows of each matrix as MFMA A-fragments in VGPRs, split-precision
// (hi fp16 + 2^-11*lo fp16 on Whh0/Wih1/Wih0; absmax 1.22e-4 vs 8.84e-4
// threshold). Layer 1 skewed one step behind layer 0 -> ONE flag barrier per
// round: round r computes h0[r] and h1[r-1] from h0[r-1], h1[r-2].
//
// Workspace (<4MB):
//   [0, 1KB)           flags: u32 per (cluster,wg)
//   [64KB, 576KB)      h exchange: [parity2][cluster8][layer2][b16][ch512] fp16
//   [640KB, 640KB+3MB) xTw: [slot3][cluster8][tau32][b16][d128] fp16
// ============================================================================

typedef _Float16 half8 __attribute__((ext_vector_type(8)));
typedef float f32x4 __attribute__((ext_vector_type(4)));
typedef unsigned long long u64;
typedef u64 u64x2 __attribute__((ext_vector_type(2)));

#define MFMA16(a, b, c) __builtin_amdgcn_mfma_f32_16x16x32_f16((a), (b), (c), 0, 0, 0)

#define WS_FLAGS_OFF 0
#define WS_EXCH_OFF (64 << 10)
#define WS_XTW_OFF (640 << 10)

__device__ __forceinline__ float sigf(float x) {
  return __builtin_amdgcn_rcpf(1.f + exp2f(-1.44269504f * x));
}
__device__ __forceinline__ float tanhf_(float x) {
  return 1.f - 2.f * __builtin_amdgcn_rcpf(1.f + exp2f(2.88539008f * x));
}
__device__ __forceinline__ unsigned short f2h(float x) {
  _Float16 h = (_Float16)x;  // RNE
  unsigned short b;
  __builtin_memcpy(&b, &h, 2);
  return b;
}

// split 8 fp32 weights -> hi fp16 + lo fp16 (lo = (w - hi) * 2^11)
__device__ __forceinline__ void cvt_split(const f32x4& a, const f32x4& b,
                                          half8& hi, half8& lo) {
#pragma unroll
  for (int i = 0; i < 4; ++i) {
    float w0 = a[i], w1 = b[i];
    _Float16 h0 = (_Float16)w0, h1 = (_Float16)w1;
    hi[i] = h0;
    hi[i + 4] = h1;
    lo[i] = (_Float16)((w0 - (float)h0) * 2048.0f);
    lo[i + 4] = (_Float16)((w1 - (float)h1) * 2048.0f);
  }
}
// scale a fragment by 2^-11 (exact exponent shift; v_pk_mul_f16)
__device__ __forceinline__ half8 hscale(half8 v) {
  half8 r;
#pragma unroll
  for (int i = 0; i < 8; ++i) r[i] = v[i] * (_Float16)4.8828125e-4f;
  return r;
}

// ---------------------------------------------------------------------------
// Prepass: fill xTw window 0 (t=0..31) slot 0, zero flags and out.
// ---------------------------------------------------------------------------
__global__ void __launch_bounds__(256) prep_kernel(const float* __restrict__ x,
                                                   _Float16* __restrict__ xTw,
                                                   unsigned* __restrict__ flags,
                                                   float* __restrict__ out) {
  const int bid = blockIdx.x;  // 128 = 8c * 16b
  const int c = bid >> 4, b16 = bid & 15;
  const int tid = threadIdx.x;
  if (bid == 0) {
    flags[tid] = 0;   // 256 flags
    out[tid] = 0.f;   // out_size = B*OUT = 256
  }
  const int d = tid & 127, th = tid >> 7;  // th: tau half (0/1)
  const float* src = x + ((size_t)(c * 16 + b16) * 128 + d) * 1024 + th * 16;
  _Float16* dst = xTw + ((size_t)c * 32 + th * 16) * (16 * 128) + b16 * 128 + d;
#pragma unroll
  for (int i = 0; i < 16; ++i) dst[(size_t)i * (16 * 128)] = (_Float16)src[i];
}

// ---------------------------------------------------------------------------
// Persistent scan kernel. MFMA 16x16x32 f16 layouts (verified R1-R3):
//   A[m=lane&15][k=(lane>>4)*8+j], B[k][n=lane&15], D[m=(lane>>4)*4+reg][n].
// ---------------------------------------------------------------------------
__global__ void __launch_bounds__(256, 1) lstm_scan(
    const float* __restrict__ Whh0, const float* __restrict__ bih0,
    const float* __restrict__ bhh0, const float* __restrict__ Wih1,
    const float* __restrict__ Whh1, const float* __restrict__ bih1,
    const float* __restrict__ bhh1, const float* __restrict__ fcW,
    const float* __restrict__ fcb, const float* __restrict__ Wih0,
    const float* __restrict__ x, unsigned* __restrict__ flags,
    unsigned short* __restrict__ exch, _Float16* __restrict__ xTw,
    float* __restrict__ out) {
  __shared__ __align__(16) _Float16 hbuf[2][16][520];
  __shared__ __align__(16) unsigned short hout[2][16][16];  // [layer][b][ch16]

  const int tid = threadIdx.x;
  const int c = blockIdx.x >> 5;   // cluster 0..7
  const int wg = blockIdx.x & 31;  // wg in cluster
  const int wave = tid >> 6;
  const int lane = tid & 63;
  const int q = lane >> 4;
  const int bb = lane & 15;
  const int wcl = wg * 4 + wave;  // wave id in cluster: 0..127
  const int chbase = wcl * 4;     // this wave's 4 hidden channels
  const int m = lane & 15;        // A-fragment row id for this lane
  const int arow = (m & 3) * 512 + chbase + (m >> 2);  // i,f,g,o gate order
  unsigned short* xtw16 = (unsigned short*)xTw;
  u64* exch64 = (u64*)exch;

  // ---- one-time: weight A-fragments (hi for all; lo for Whh0/Wih1/Wih0) ----
  half8 fW0[16], fW0lo[16], fW1i[16], fW1ilo[16], fW1h[16], fX[4], fXlo[4];
  {
    const float* p0 = Whh0 + (size_t)arow * 512 + q * 8;
    const float* p1 = Wih1 + (size_t)arow * 512 + q * 8;
    const float* p2 = Whh1 + (size_t)arow * 512 + q * 8;
#pragma unroll
    for (int kt = 0; kt < 16; ++kt) {
      f32x4 a0 = *(const f32x4*)(p0 + kt * 32), b0 = *(const f32x4*)(p0 + kt * 32 + 4);
      cvt_split(a0, b0, fW0[kt], fW0lo[kt]);
      f32x4 a1 = *(const f32x4*)(p1 + kt * 32), b1 = *(const f32x4*)(p1 + kt * 32 + 4);
      cvt_split(a1, b1, fW1i[kt], fW1ilo[kt]);
      f32x4 a2 = *(const f32x4*)(p2 + kt * 32), b2 = *(const f32x4*)(p2 + kt * 32 + 4);
      half8 dummy;
      cvt_split(a2, b2, fW1h[kt], dummy);  // hi only
    }
    const float* p3 = Wih0 + (size_t)arow * 128 + q * 8;
#pragma unroll
    for (int kt = 0; kt < 4; ++kt) {
      f32x4 a3 = *(const f32x4*)(p3 + kt * 32), b3 = *(const f32x4*)(p3 + kt * 32 + 4);
      cvt_split(a3, b3, fX[kt], fXlo[kt]);
    }
  }

  float b0v[4], b1v[4];
#pragma unroll
  for (int g = 0; g < 4; ++g) {
    int rrow = g * 512 + chbase + q;
    b0v[g] = bih0[rrow] + bhh0[rrow];
    b1v[g] = bih1[rrow] + bhh1[rrow];
  }
  const int ch = chbase + q;
  const float fcw0 = fcW[ch], fcw1 = fcW[512 + ch];

  float c0 = 0.f, c1 = 0.f;
  unsigned* myflag = flags + (c * 32 + wg);
  const unsigned* spinflag = flags + (c * 32 + (lane & 31));

  const int T = 1024;
  for (int r = 0; r <= T; ++r) {
    const bool L0 = (r < T);
    const bool L1 = (r > 0);
    const bool L1h = (r > 1);

    // ---- x refresh: cluster writes ONE tau plane (tau=r&31) of window w+1.
    //      WG wg owns (b = wg>>1, d-half = wg&1); lane = d -> coalesced
    //      contiguous stores. Read from x is 4KB-strided (MALL-resident). ----
    if (wave == 2 && r < 992) {
      const int wnext = (r >> 5) + 1, sw = wnext % 3, rw = r & 31;
      const int xb = wg >> 1, xd = (wg & 1) * 64 + lane;
      float xv = x[((size_t)(c * 16 + xb) * 128 + xd) * 1024 + wnext * 32 + rw];
      __hip_atomic_store(
          xtw16 + (((size_t)(sw * 8 + c) * 32 + rw) * 16 + xb) * 128 + xd,
          f2h(xv), __ATOMIC_RELAXED, __HIP_MEMORY_SCOPE_AGENT);
    }

    // x fragments for t=r (atomic u64 loads, issued before the spin; slot
    // validity is guaranteed >=1 window in advance by the flag chain)
    half8 xf[4];
    if (L0) {
      const int s = (r >> 5) % 3, tau = r & 31;
      const u64* xp =
          (const u64*)xtw16 + (((size_t)(s * 8 + c) * 32 + tau) * 16 + bb) * 32;
#pragma unroll
      for (int kt = 0; kt < 4; ++kt) {
        u64x2 t2;
        t2.x = __hip_atomic_load(xp + kt * 8 + q * 2, __ATOMIC_RELAXED,
                                 __HIP_MEMORY_SCOPE_AGENT);
        t2.y = __hip_atomic_load(xp + kt * 8 + q * 2 + 1, __ATOMIC_RELAXED,
                                 __HIP_MEMORY_SCOPE_AGENT);
        xf[kt] = __builtin_bit_cast(half8, t2);
      }
    }

    if (r > 0) {
      // all 4 waves spin (no pre-barrier); own WG's flag is in the set, so no
      // wave can run ahead of its wave 0's publication.
      int guard = 0;
      for (;;) {
        unsigned v = __hip_atomic_load(spinflag, __ATOMIC_RELAXED,
                                       __HIP_MEMORY_SCOPE_AGENT);
        if (__ballot(v >= (unsigned)r) == ~0ull) break;
        if (++guard > (1 << 24)) break;  // deadlock bailout
      }
      asm volatile("" ::: "memory");  // keep staging loads below the spin
      // stage h0[r-1], h1[r-2] (32KB) into padded LDS rows
      const int p = (r - 1) & 1;
      const u64* src = exch64 + ((size_t)p * 8 + c) * (32 * 128) + tid;
#pragma unroll
      for (int hh = 0; hh < 2; ++hh) {
        u64 v[8];
#pragma unroll
        for (int i = 0; i < 8; ++i)
          v[i] = __hip_atomic_load(src + (hh * 8 + i) * 256, __ATOMIC_RELAXED,
                                   __HIP_MEMORY_SCOPE_AGENT);
#pragma unroll
        for (int i = 0; i < 8; ++i) {
          int f = (hh * 8 + i) * 256 + tid;
          int row = f >> 7, off = f & 127;  // row = layer*16 + b
          *((u64*)(&hbuf[row >> 4][row & 15][0]) + off) = v[i];
        }
      }
    }
    __syncthreads();  // staging visible to all waves

    // ---- MFMA chains (split accumulators; lo-chains share accs via 2^-11-
    //      scaled B operands) ----
    f32x4 accX = {b0v[0], b0v[1], b0v[2], b0v[3]};
    f32x4 a0 = {0.f, 0.f, 0.f, 0.f}, a0b = {0.f, 0.f, 0.f, 0.f};
    if (L0) {
#pragma unroll
      for (int kt = 0; kt < 4; ++kt) {
        accX = MFMA16(fX[kt], xf[kt], accX);
        accX = MFMA16(fXlo[kt], hscale(xf[kt]), accX);
      }
    }
    f32x4 a1 = {b1v[0], b1v[1], b1v[2], b1v[3]};
    f32x4 a1b = {0.f, 0.f, 0.f, 0.f}, a1c = {0.f, 0.f, 0.f, 0.f},
          a1d = {0.f, 0.f, 0.f, 0.f};
    if (L1) {
#pragma unroll
      for (int kt = 0; kt < 8; ++kt) {
        half8 hA = *(const half8*)(&hbuf[0][bb][kt * 32 + q * 8]);
        half8 hB = *(const half8*)(&hbuf[0][bb][(kt + 8) * 32 + q * 8]);
        half8 hAs = hscale(hA), hBs = hscale(hB);
        if (L0) {
          a0 = MFMA16(fW0[kt], hA, a0);
          a0b = MFMA16(fW0[kt + 8], hB, a0b);
          a0 = MFMA16(fW0lo[kt], hAs, a0);
          a0b = MFMA16(fW0lo[kt + 8], hBs, a0b);
        }
        a1 = MFMA16(fW1i[kt], hA, a1);
        a1b = MFMA16(fW1i[kt + 8], hB, a1b);
        a1 = MFMA16(fW1ilo[kt], hAs, a1);
        a1b = MFMA16(fW1ilo[kt + 8], hBs, a1b);
      }
    }
    if (L1h) {
#pragma unroll
      for (int kt = 0; kt < 8; ++kt) {
        half8 hC = *(const half8*)(&hbuf[1][bb][kt * 32 + q * 8]);
        half8 hD = *(const half8*)(&hbuf[1][bb][(kt + 8) * 32 + q * 8]);
        a1c = MFMA16(fW1h[kt], hC, a1c);
        a1d = MFMA16(fW1h[kt + 8], hD, a1d);
      }
    }

    // ---- epilogues: lane (q,bb) owns (channel chbase+q, batch c*16+bb);
    //      h goes to LDS (hout), published coalesced by wave 0 below ----
    if (L0) {
      f32x4 g0 = accX + a0 + a0b;
      float gi = sigf(g0.x), gf = sigf(g0.y), gg = tanhf_(g0.z), go = sigf(g0.w);
      c0 = gf * c0 + gi * gg;
      float h0v = go * tanhf_(c0);
      hout[0][bb][wave * 4 + q] = f2h(h0v);
    }
    if (L1) {
      f32x4 g1 = a1 + a1b + a1c + a1d;
      float gi = sigf(g1.x), gf = sigf(g1.y), gg = tanhf_(g1.z), go = sigf(g1.w);
      c1 = gf * c1 + gi * gg;
      float h1v = go * tanhf_(c1);
      if (r == T) {
        // fc head (out zeroed by prep_kernel each call)
        float s0 = h1v * fcw0, s1 = h1v * fcw1;
        s0 += __shfl_xor(s0, 16); s0 += __shfl_xor(s0, 32);
        s1 += __shfl_xor(s1, 16); s1 += __shfl_xor(s1, 32);
        if (q == 0) {
          atomicAdd(out + (size_t)(c * 16 + bb) * 2 + 0, s0);
          atomicAdd(out + (size_t)(c * 16 + bb) * 2 + 1, s1);
        }
        if (wcl == 0 && lane < 32)
          atomicAdd(out + (size_t)(c * 16 + (lane & 15)) * 2 + (lane >> 4),
                    fcb[lane >> 4]);
      } else {
        hout[1][bb][wave * 4 + q] = f2h(h1v);
      }
    }
    if (r == T) break;
    __syncthreads();  // hout complete (also drains every wave's vmcnt,
                      // covering wave 2's refresh stores before the flag)
    if (wave == 0) {
      // publish this WG's h chunk: 2 u64/lane, 32B contiguous segments.
      // u64 index f: layer=f>>6, b=(f>>2)&15, q4=f&3; global halfword addr
      // ((p*8+c)*32+layer*16+b)*512 + wg*16 + q4*4.
      const int p2 = r & 1;
#pragma unroll
      for (int j = 0; j < 2; ++j) {
        int f = j * 64 + lane;
        int layer = f >> 6, b_ = (f >> 2) & 15, q4 = f & 3;
        u64 v = ((const u64*)hout)[f];
        __hip_atomic_store(
            exch64 + (((size_t)p2 * 8 + c) * 32 + layer * 16 + b_) * 128 +
                wg * 4 + q4,
            v, __ATOMIC_RELAXED, __HIP_MEMORY_SCOPE_AGENT);
      }
      asm volatile("s_waitcnt vmcnt(0)" ::: "memory");  // stores at MALL
      if (lane == 0)
        __hip_atomic_store(myflag, (unsigned)(r + 1), __ATOMIC_RELAXED,
                           __HIP_MEMORY_SCOPE_AGENT);
    }
  }
}

extern "C" void kernel_launch(void* const* d_in, const int* in_sizes, int n_in,
                              void* d_out, int out_size, void* d_ws,
                              size_t ws_size, hipStream_t stream) {
  const float* x = (const float*)d_in[0];
  const float* Wih0 = (const float*)d_in[1];
  const float* Whh0 = (const float*)d_in[2];
  const float* bih0 = (const float*)d_in[3];
  const float* bhh0 = (const float*)d_in[4];
  const float* Wih1 = (const float*)d_in[5];
  const float* Whh1 = (const float*)d_in[6];
  const float* bih1 = (const float*)d_in[7];
  const float* bhh1 = (const float*)d_in[8];
  const float* fcW = (const float*)d_in[9];
  const float* fcb = (const float*)d_in[10];

  char* ws = (char*)d_ws;  // uses < 4MB total
  unsigned* flags = (unsigned*)(ws + WS_FLAGS_OFF);
  unsigned short* exch = (unsigned short*)(ws + WS_EXCH_OFF);
  _Float16* xTw = (_Float16*)(ws + WS_XTW_OFF);
  float* out = (float*)d_out;

  prep_kernel<<<dim3(128), dim3(256), 0, stream>>>(x, xTw, flags, out);
  lstm_scan<<<dim3(256), dim3(256), 0, stream>>>(Whh0, bih0, bhh0, Wih1, Whh1,
                                                 bih1, bhh1, fcW, fcb, Wih0, x,
                                                 flags, exch, xTw, out);
}